// Round 1
// baseline (556.530 us; speedup 1.0000x reference)
//
#include <hip/hip_runtime.h>
#include <hip/hip_bf16.h>

// Problem constants
#define BB 4
#define LL 2048
#define SS 2048
#define EE 1024
#define HH 16
#define DD 64
#define MM (BB * LL)   // 8192 rows for all projections
#define LOG2E 1.44269504088896340736f

typedef unsigned short u16;
typedef u16   u16x4  __attribute__((ext_vector_type(4)));
typedef u16   u16x8  __attribute__((ext_vector_type(8)));
typedef float f32x4  __attribute__((ext_vector_type(4)));
typedef __bf16 bf16x4 __attribute__((ext_vector_type(4)));
typedef __bf16 bf16x8 __attribute__((ext_vector_type(8)));

__device__ __forceinline__ u16 f2bf(float x) {
    unsigned u = __float_as_uint(x);
    u += 0x7fffu + ((u >> 16) & 1u);       // RNE (inputs finite)
    return (u16)(u >> 16);
}
__device__ __forceinline__ float bf2f(u16 b) {
    return __uint_as_float(((unsigned)b) << 16);
}

// async global->LDS, 16B per lane; LDS dest is wave-uniform base + lane*16
__device__ __forceinline__ void gload16(const u16* g, u16* l) {
    __builtin_amdgcn_global_load_lds(
        (const __attribute__((address_space(1))) void*)g,
        (__attribute__((address_space(3))) void*)l, 16, 0, 0);
}

// ---------------------------------------------------------------------------
// Generic fp32 -> bf16 cast, 8 elems/thread
__global__ __launch_bounds__(256) void f32_to_bf16_kernel(
    const float* __restrict__ in, u16* __restrict__ out)
{
    size_t idx = ((size_t)blockIdx.x * 256 + threadIdx.x) * 8;
    f32x4 a = *(const f32x4*)(in + idx);
    f32x4 b = *(const f32x4*)(in + idx + 4);
    u16x8 o;
#pragma unroll
    for (int j = 0; j < 4; j++) { o[j] = f2bf(a[j]); o[4 + j] = f2bf(b[j]); }
    *(u16x8*)(out + idx) = o;
}

// ---------------------------------------------------------------------------
// comb[l][s] = bf16((attn_bias + attn_mask) * log2(e))  -- log2 domain for exp2
__global__ __launch_bounds__(256) void combine_bias_kernel(
    const float* __restrict__ bias, const float* __restrict__ mask,
    u16* __restrict__ comb)
{
    int idx = (blockIdx.x * 256 + threadIdx.x) * 8;
    f32x4 a0 = *(const f32x4*)(bias + idx);
    f32x4 a1 = *(const f32x4*)(bias + idx + 4);
    f32x4 m0 = *(const f32x4*)(mask + idx);
    f32x4 m1 = *(const f32x4*)(mask + idx + 4);
    u16x8 o;
#pragma unroll
    for (int j = 0; j < 4; j++) {
        o[j]     = f2bf((a0[j] + m0[j]) * LOG2E);
        o[4 + j] = f2bf((a1[j] + m1[j]) * LOG2E);
    }
    *(u16x8*)(comb + idx) = o;
}

// ---------------------------------------------------------------------------
// C[m][n] = (sum_k A[m][k]*Bw[n][k] + bias[n]) * scale
// A, Bw bf16 [.,K]; 128x128 tile, BK=64, 256 threads (4 waves 2x2).
// global_load_lds (16B) staging into linear [128][64] LDS, double-buffered
// 2-phase: issue stage(next) -> compute(cur) -> barrier (drains vmcnt).
template <int OUTBF16>
__global__ __launch_bounds__(256, 2) void gemm_bt_bf16(
    const u16* __restrict__ A, const u16* __restrict__ Bw,
    const float* __restrict__ bias, void* __restrict__ Cp,
    int M, int N, int K, float scale)
{
    __shared__ __align__(16) u16 As[2][128 * 64];
    __shared__ __align__(16) u16 Bs[2][128 * 64];
    const int tid = threadIdx.x;
    const int lane = tid & 63, wave = tid >> 6;
    const int quad = lane >> 4, ln = lane & 15;
    const int wm = (wave & 1) * 64, wn = (wave >> 1) * 64;
    const int m0 = blockIdx.x * 128, n0 = blockIdx.y * 128;

    const int r8 = lane >> 3, c8 = lane & 7;
    const u16* Ag = A  + (size_t)m0 * K + c8 * 8;
    const u16* Bg = Bw + (size_t)n0 * K + c8 * 8;

    f32x4 acc[4][4];
#pragma unroll
    for (int mt = 0; mt < 4; mt++)
#pragma unroll
        for (int nt = 0; nt < 4; nt++) acc[mt][nt] = (f32x4){0.f, 0.f, 0.f, 0.f};

    // stage one 128x64 K-slice of A and B into buffer `buf`
    auto stage = [&](int buf, int k0) {
#pragma unroll
        for (int i = 0; i < 4; i++) {
            int ch = i * 4 + wave;             // 16 chunks of 1KB each
            int row = ch * 8 + r8;             // 8 rows per chunk
            gload16(Ag + (size_t)row * K + k0, &As[buf][ch * 512]);
            gload16(Bg + (size_t)row * K + k0, &Bs[buf][ch * 512]);
        }
    };

    stage(0, 0);
    int buf = 0;
    const int KT = K >> 6;
    for (int kt = 0; kt < KT; kt++) {
        __syncthreads();                       // stage(buf) landed; prev reads done
        if (kt + 1 < KT) stage(buf ^ 1, (kt + 1) << 6);
        __builtin_amdgcn_s_setprio(1);
#pragma unroll
        for (int ks = 0; ks < 2; ks++) {
            bf16x8 af[4], bfg[4];
#pragma unroll
            for (int mt = 0; mt < 4; mt++)
                af[mt] = *(const bf16x8*)(&As[buf][(wm + mt * 16 + ln) * 64 + ks * 32 + quad * 8]);
#pragma unroll
            for (int nt = 0; nt < 4; nt++)
                bfg[nt] = *(const bf16x8*)(&Bs[buf][(wn + nt * 16 + ln) * 64 + ks * 32 + quad * 8]);
#pragma unroll
            for (int mt = 0; mt < 4; mt++)
#pragma unroll
                for (int nt = 0; nt < 4; nt++)
                    acc[mt][nt] = __builtin_amdgcn_mfma_f32_16x16x32_bf16(
                        af[mt], bfg[nt], acc[mt][nt], 0, 0, 0);
        }
        __builtin_amdgcn_s_setprio(0);
        buf ^= 1;
    }

#pragma unroll
    for (int nt = 0; nt < 4; nt++) {
        int n = n0 + wn + nt * 16 + ln;
        float bn = bias[n];
#pragma unroll
        for (int mt = 0; mt < 4; mt++) {
#pragma unroll
            for (int r = 0; r < 4; r++) {
                int m = m0 + wm + mt * 16 + quad * 4 + r;
                float val = (acc[mt][nt][r] + bn) * scale;
                if (OUTBF16) ((u16*)Cp)[(size_t)m * N + n] = f2bf(val);
                else         ((float*)Cp)[(size_t)m * N + n] = val;
            }
        }
    }
}

// ---------------------------------------------------------------------------
// vt[b][h][d][s] = v_bf[b][s][h*64+d]
__global__ __launch_bounds__(256) void transpose_v_kernel(
    const u16* __restrict__ vb, u16* __restrict__ vt)
{
    __shared__ __align__(16) u16 t[64 * 72];
    const int bh = blockIdx.y, b = bh >> 4, h = bh & 15;
    const int s0 = blockIdx.x * 64;
    const int tid = threadIdx.x;
#pragma unroll
    for (int i = 0; i < 2; i++) {
        int chunk = tid + 256 * i;                    // 512 = 64 rows x 8
        int row = chunk >> 3, c = chunk & 7;
        u16x8 v = *(const u16x8*)(vb + (size_t)(b * SS + s0 + row) * EE + h * 64 + c * 8);
        *(u16x8*)(t + row * 72 + c * 8) = v;
    }
    __syncthreads();
#pragma unroll
    for (int i = 0; i < 2; i++) {
        int chunk = tid + 256 * i;
        int d = chunk >> 3, c = chunk & 7;
        u16x8 o;
#pragma unroll
        for (int j = 0; j < 8; j++) o[j] = t[(c * 8 + j) * 72 + d];
        *(u16x8*)(vt + (size_t)(bh * 64 + d) * SS + s0 + c * 8) = o;
    }
}

// ---------------------------------------------------------------------------
// Attention: per block 128 q-rows of one (b,h); 4 waves, 32 q/wave.
// S^T = K*Q^T; q pre-scaled by 0.125*log2e, comb in log2 domain -> bare exp2.
// Bias fragments init the QK accumulator (loaded before mid-barrier so its
// vmcnt(0) drain covers them). 3 blocks/CU via launch_bounds(256,3).
__global__ __launch_bounds__(256, 3) void attn_kernel(
    const u16* __restrict__ qb,   // [B,L,E] bf16, pre-scaled (0.125*log2e)
    const u16* __restrict__ kb,   // [B,S,E] bf16
    const u16* __restrict__ vt,   // [B*H,64,S] bf16
    const u16* __restrict__ comb, // [L,S] bf16 (mask+bias)*log2e
    u16* __restrict__ attn)       // [B,L,E] bf16
{
    __shared__ __align__(16) u16 KPs[128 * 136];  // union: K tile (stride 72) / P^T (stride 136)
    __shared__ __align__(16) u16 Vs[64 * 136];    // V^T tile [d][s]
    const int tid = threadIdx.x, lane = tid & 63, wave = tid >> 6;
    const int quad = lane >> 4, ln = lane & 15;
    const int bh = blockIdx.y, b = bh >> 4, h = bh & 15;
    const int q0 = blockIdx.x * 128;
    const int qloc0 = wave * 32;                  // wave's first local q row

    bf16x8 qf[2][2];
#pragma unroll
    for (int qg = 0; qg < 2; qg++)
#pragma unroll
        for (int ks = 0; ks < 2; ks++)
            qf[qg][ks] = *(const bf16x8*)(qb + (size_t)(b * LL + q0 + qloc0 + 16 * qg + ln) * EE
                                          + h * 64 + ks * 32 + quad * 8);

    const u16* cb0 = comb + (size_t)(q0 + qloc0 + ln) * SS + quad * 4;  // qg=0
    const u16* cb1 = cb0 + (size_t)16 * SS;                              // qg=1

    f32x4 o[4][2];
#pragma unroll
    for (int mt = 0; mt < 4; mt++) { o[mt][0] = (f32x4){0,0,0,0}; o[mt][1] = (f32x4){0,0,0,0}; }
    f32x4 ls0 = (f32x4){0,0,0,0}, ls1 = (f32x4){0,0,0,0};   // 4 independent sum chains each

    u16x8 kreg[4], vreg[4];
    auto load_kv = [&](int s0) {
#pragma unroll
        for (int i = 0; i < 4; i++) {
            int chunk = tid + 256 * i, row = chunk >> 3, c = chunk & 7;   // 128 x 8
            kreg[i] = *(const u16x8*)(kb + (size_t)(b * SS + s0 + row) * EE + h * 64 + c * 8);
        }
#pragma unroll
        for (int i = 0; i < 4; i++) {
            int chunk = tid + 256 * i, row = chunk >> 4, c = chunk & 15;  // 64 x 16
            vreg[i] = *(const u16x8*)(vt + (size_t)(bh * 64 + row) * SS + s0 + c * 8);
        }
    };
    load_kv(0);

    for (int s0 = 0; s0 < SS; s0 += 128) {
        __syncthreads();                           // prev iter's P/V LDS reads done
#pragma unroll
        for (int i = 0; i < 4; i++) {              // K tile -> union (stride 72)
            int chunk = tid + 256 * i, row = chunk >> 3, c = chunk & 7;
            *(u16x8*)(KPs + row * 72 + c * 8) = kreg[i];
        }
#pragma unroll
        for (int i = 0; i < 4; i++) {              // V^T tile
            int chunk = tid + 256 * i, row = chunk >> 4, c = chunk & 15;
            *(u16x8*)(Vs + row * 136 + c * 8) = vreg[i];
        }
        // bias fragments: issued before the barrier -> its vmcnt(0) drain covers them
        u16x4 bfr[8][2];
#pragma unroll
        for (int mt = 0; mt < 8; mt++) {
            bfr[mt][0] = *(const u16x4*)(cb0 + s0 + mt * 16);
            bfr[mt][1] = *(const u16x4*)(cb1 + s0 + mt * 16);
        }
        __syncthreads();

        if (s0 + 128 < SS) load_kv(s0 + 128);      // prefetch next K/V into regs

        // S^T accumulator initialized with bias (log2 domain)
        f32x4 st[8][2];
#pragma unroll
        for (int mt = 0; mt < 8; mt++)
#pragma unroll
            for (int r = 0; r < 4; r++) {
                st[mt][0][r] = bf2f(bfr[mt][0][r]);
                st[mt][1][r] = bf2f(bfr[mt][1][r]);
            }

        // S^T[s][q] = bias + sum_d K[s][d] * Q[q][d]
        __builtin_amdgcn_s_setprio(1);
#pragma unroll
        for (int mt = 0; mt < 8; mt++) {
            bf16x8 a0 = *(const bf16x8*)(KPs + (mt * 16 + ln) * 72 + quad * 8);
            bf16x8 a1 = *(const bf16x8*)(KPs + (mt * 16 + ln) * 72 + 32 + quad * 8);
            st[mt][0] = __builtin_amdgcn_mfma_f32_16x16x32_bf16(a0, qf[0][0], st[mt][0], 0, 0, 0);
            st[mt][0] = __builtin_amdgcn_mfma_f32_16x16x32_bf16(a1, qf[0][1], st[mt][0], 0, 0, 0);
            st[mt][1] = __builtin_amdgcn_mfma_f32_16x16x32_bf16(a0, qf[1][0], st[mt][1], 0, 0, 0);
            st[mt][1] = __builtin_amdgcn_mfma_f32_16x16x32_bf16(a1, qf[1][1], st[mt][1], 0, 0, 0);
        }
        __builtin_amdgcn_s_setprio(0);

        // exp2 + native bf16 pack (compiler emits v_cvt_pk_bf16_f32)
        bf16x4 p[8][2];
#pragma unroll
        for (int mt = 0; mt < 8; mt++)
#pragma unroll
            for (int r = 0; r < 4; r++) {
                float e0 = __builtin_amdgcn_exp2f(st[mt][0][r]);
                float e1 = __builtin_amdgcn_exp2f(st[mt][1][r]);
                ls0[r] += e0; ls1[r] += e1;
                p[mt][0][r] = (__bf16)e0;
                p[mt][1][r] = (__bf16)e1;
            }

        __syncthreads();                           // all waves done reading K tile

#pragma unroll
        for (int mt = 0; mt < 8; mt++) {           // P^T -> union (stride 136), wave-private rows
            *(bf16x4*)(KPs + (qloc0 + ln) * 136 + mt * 16 + quad * 4)      = p[mt][0];
            *(bf16x4*)(KPs + (qloc0 + 16 + ln) * 136 + mt * 16 + quad * 4) = p[mt][1];
        }

        // O^T[d][q] += sum_s V^T[d][s] * P[s][q]
#pragma unroll
        for (int ks = 0; ks < 4; ks++) {
            bf16x8 pf0 = *(const bf16x8*)(KPs + (qloc0 + ln) * 136 + ks * 32 + quad * 8);
            bf16x8 pf1 = *(const bf16x8*)(KPs + (qloc0 + 16 + ln) * 136 + ks * 32 + quad * 8);
            __builtin_amdgcn_s_setprio(1);
#pragma unroll
            for (int mt = 0; mt < 4; mt++) {
                bf16x8 a = *(const bf16x8*)(Vs + (mt * 16 + ln) * 136 + ks * 32 + quad * 8);
                o[mt][0] = __builtin_amdgcn_mfma_f32_16x16x32_bf16(a, pf0, o[mt][0], 0, 0, 0);
                o[mt][1] = __builtin_amdgcn_mfma_f32_16x16x32_bf16(a, pf1, o[mt][1], 0, 0, 0);
            }
            __builtin_amdgcn_s_setprio(0);
        }
    }

    // softmax denominator: merge 4 chains, then reduce across quads
    float lsum0 = (ls0[0] + ls0[1]) + (ls0[2] + ls0[3]);
    float lsum1 = (ls1[0] + ls1[1]) + (ls1[2] + ls1[3]);
    lsum0 += __shfl_xor(lsum0, 16); lsum0 += __shfl_xor(lsum0, 32);
    lsum1 += __shfl_xor(lsum1, 16); lsum1 += __shfl_xor(lsum1, 32);
    float inv0 = 1.f / lsum0, inv1 = 1.f / lsum1;

    // O^T -> LDS (wave-private rows) -> coalesced store
#pragma unroll
    for (int mt = 0; mt < 4; mt++) {
        bf16x4 p0, p1;
#pragma unroll
        for (int r = 0; r < 4; r++) {
            p0[r] = (__bf16)(o[mt][0][r] * inv0);
            p1[r] = (__bf16)(o[mt][1][r] * inv1);
        }
        *(bf16x4*)(KPs + (qloc0 + ln) * 136 + mt * 16 + quad * 4)      = p0;
        *(bf16x4*)(KPs + (qloc0 + 16 + ln) * 136 + mt * 16 + quad * 4) = p1;
    }
#pragma unroll
    for (int i = 0; i < 4; i++) {
        int j = lane + 64 * i;                     // 256 chunks over wave's 32 rows
        int r = j >> 3, c = j & 7;
        u16x8 v = *(const u16x8*)(KPs + (qloc0 + r) * 136 + c * 8);
        *(u16x8*)(attn + (size_t)(b * LL + q0 + qloc0 + r) * EE + h * 64 + c * 8) = v;
    }
}

// ---------------------------------------------------------------------------
extern "C" void kernel_launch(void* const* d_in, const int* in_sizes, int n_in,
                              void* d_out, int out_size, void* d_ws, size_t ws_size,
                              hipStream_t stream)
{
    (void)in_sizes; (void)n_in; (void)out_size; (void)ws_size;
    const float* query     = (const float*)d_in[0];
    const float* key       = (const float*)d_in[1];
    const float* value     = (const float*)d_in[2];
    const float* attn_bias = (const float*)d_in[3];
    const float* attn_mask = (const float*)d_in[4];
    const float* Wqkv      = (const float*)d_in[5];
    const float* bqkv      = (const float*)d_in[6];
    const float* Wo        = (const float*)d_in[7];
    const float* bo        = (const float*)d_in[8];
    float* out = (float*)d_out;

    // workspace layout (~100.7 MB, unchanged)
    u16* wq_bf = (u16*)d_ws;                 // 3*EE*EE
    u16* wo_bf = wq_bf + 3 * EE * EE;        // EE*EE
    u16* comb  = wo_bf + EE * EE;            // LL*SS
    u16* q_bf  = comb + (size_t)LL * SS;     // MM*EE each:
    u16* k_bf  = q_bf + (size_t)MM * EE;
    u16* v_bf  = k_bf + (size_t)MM * EE;
    u16* vtr   = v_bf + (size_t)MM * EE;
    u16* attnb = vtr  + (size_t)MM * EE;
    u16* tmp   = attnb;   // input-cast scratch; free until attn_kernel (stream-serial)

    f32_to_bf16_kernel<<<3 * EE * EE / 2048, 256, 0, stream>>>(Wqkv, wq_bf);
    f32_to_bf16_kernel<<<EE * EE / 2048, 256, 0, stream>>>(Wo, wo_bf);
    combine_bias_kernel<<<(LL * SS) / 2048, 256, 0, stream>>>(attn_bias, attn_mask, comb);

    dim3 gg(MM / 128, EE / 128);
    // q pre-scaled by SCALING * log2(e) so attn uses bare exp2
    f32_to_bf16_kernel<<<(int)((size_t)MM * EE / 2048), 256, 0, stream>>>(query, tmp);
    gemm_bt_bf16<1><<<gg, 256, 0, stream>>>(tmp, wq_bf,              bqkv,          q_bf, MM, EE, EE, 0.125f * LOG2E);
    f32_to_bf16_kernel<<<(int)((size_t)MM * EE / 2048), 256, 0, stream>>>(key, tmp);
    gemm_bt_bf16<1><<<gg, 256, 0, stream>>>(tmp, wq_bf + EE * EE,     bqkv + EE,     k_bf, MM, EE, EE, 1.f);
    f32_to_bf16_kernel<<<(int)((size_t)MM * EE / 2048), 256, 0, stream>>>(value, tmp);
    gemm_bt_bf16<1><<<gg, 256, 0, stream>>>(tmp, wq_bf + 2 * EE * EE, bqkv + 2 * EE, v_bf, MM, EE, EE, 1.f);

    transpose_v_kernel<<<dim3(SS / 64, BB * HH), 256, 0, stream>>>(v_bf, vtr);

    attn_kernel<<<dim3(LL / 128, BB * HH), 256, 0, stream>>>(q_bf, k_bf, vtr, comb, attnb);

    gemm_bt_bf16<0><<<gg, 256, 0, stream>>>(attnb, wo_bf, bo, out, MM, EE, EE, 1.f);
}

// Round 2
// 454.949 us; speedup vs baseline: 1.2233x; 1.2233x over previous
//
#include <hip/hip_runtime.h>
#include <hip/hip_bf16.h>

// Problem constants
#define BB 4
#define LL 2048
#define SS 2048
#define EE 1024
#define HH 16
#define DD 64
#define MM (BB * LL)   // 8192 rows for all projections
#define LOG2E 1.44269504088896340736f

typedef unsigned short u16;
typedef u16   u16x4  __attribute__((ext_vector_type(4)));
typedef u16   u16x8  __attribute__((ext_vector_type(8)));
typedef float f32x4  __attribute__((ext_vector_type(4)));
typedef __bf16 bf16x4 __attribute__((ext_vector_type(4)));
typedef __bf16 bf16x8 __attribute__((ext_vector_type(8)));

__device__ __forceinline__ u16 f2bf(float x) {
    unsigned u = __float_as_uint(x);
    u += 0x7fffu + ((u >> 16) & 1u);       // RNE (inputs finite)
    return (u16)(u >> 16);
}
__device__ __forceinline__ float bf2f(u16 b) {
    return __uint_as_float(((unsigned)b) << 16);
}

// async global->LDS, 16B per lane; LDS dest is wave-uniform base + lane*16
__device__ __forceinline__ void gload16(const u16* g, u16* l) {
    __builtin_amdgcn_global_load_lds(
        (const __attribute__((address_space(1))) void*)g,
        (__attribute__((address_space(3))) void*)l, 16, 0, 0);
}

// ---------------------------------------------------------------------------
// Generic fp32 -> bf16 cast, 8 elems/thread
__global__ __launch_bounds__(256) void f32_to_bf16_kernel(
    const float* __restrict__ in, u16* __restrict__ out)
{
    size_t idx = ((size_t)blockIdx.x * 256 + threadIdx.x) * 8;
    f32x4 a = *(const f32x4*)(in + idx);
    f32x4 b = *(const f32x4*)(in + idx + 4);
    u16x8 o;
#pragma unroll
    for (int j = 0; j < 4; j++) { o[j] = f2bf(a[j]); o[4 + j] = f2bf(b[j]); }
    *(u16x8*)(out + idx) = o;
}

// ---------------------------------------------------------------------------
// comb[l][s] = bf16((attn_bias + attn_mask) * log2(e))  -- log2 domain for exp2
__global__ __launch_bounds__(256) void combine_bias_kernel(
    const float* __restrict__ bias, const float* __restrict__ mask,
    u16* __restrict__ comb)
{
    int idx = (blockIdx.x * 256 + threadIdx.x) * 8;
    f32x4 a0 = *(const f32x4*)(bias + idx);
    f32x4 a1 = *(const f32x4*)(bias + idx + 4);
    f32x4 m0 = *(const f32x4*)(mask + idx);
    f32x4 m1 = *(const f32x4*)(mask + idx + 4);
    u16x8 o;
#pragma unroll
    for (int j = 0; j < 4; j++) {
        o[j]     = f2bf((a0[j] + m0[j]) * LOG2E);
        o[4 + j] = f2bf((a1[j] + m1[j]) * LOG2E);
    }
    *(u16x8*)(comb + idx) = o;
}

// ---------------------------------------------------------------------------
// C[m][n] = (sum_k A[m][k]*Bw[n][k] + bias[n]) * scale
// A, Bw bf16 [.,K]; 128x128 tile, BK=64, 256 threads (4 waves 2x2).
// m97 structure: SINGLE 32KB LDS buffer, barrier -> global_load_lds stage ->
// barrier -> MFMA per K-step. ~136 unified regs -> 3 blocks/CU; inter-block
// overlap hides the stage drain (m114). No setprio (null on 2-barrier GEMM).
template <int OUTBF16>
__global__ __launch_bounds__(256, 2) void gemm_bt_bf16(
    const u16* __restrict__ A, const u16* __restrict__ Bw,
    const float* __restrict__ bias, void* __restrict__ Cp,
    int M, int N, int K, float scale)
{
    __shared__ __align__(16) u16 As[128 * 64];
    __shared__ __align__(16) u16 Bs[128 * 64];
    const int tid = threadIdx.x;
    const int lane = tid & 63, wave = tid >> 6;
    const int quad = lane >> 4, ln = lane & 15;
    const int wm = (wave & 1) * 64, wn = (wave >> 1) * 64;
    const int m0 = blockIdx.x * 128, n0 = blockIdx.y * 128;

    const int r8 = lane >> 3, c8 = lane & 7;
    const u16* Ag = A  + (size_t)m0 * K + c8 * 8;
    const u16* Bg = Bw + (size_t)n0 * K + c8 * 8;

    f32x4 acc[4][4];
#pragma unroll
    for (int mt = 0; mt < 4; mt++)
#pragma unroll
        for (int nt = 0; nt < 4; nt++) acc[mt][nt] = (f32x4){0.f, 0.f, 0.f, 0.f};

    for (int k0 = 0; k0 < K; k0 += 64) {
        __syncthreads();                       // prev compute done reading LDS
#pragma unroll
        for (int i = 0; i < 4; i++) {
            int ch = i * 4 + wave;             // 16 chunks of 1KB each
            int row = ch * 8 + r8;             // 8 rows per chunk
            gload16(Ag + (size_t)row * K + k0, &As[ch * 512]);
            gload16(Bg + (size_t)row * K + k0, &Bs[ch * 512]);
        }
        __syncthreads();                       // stage landed (vmcnt drain)

#pragma unroll
        for (int ks = 0; ks < 2; ks++) {
            bf16x8 af[4], bfg[4];
#pragma unroll
            for (int mt = 0; mt < 4; mt++)
                af[mt] = *(const bf16x8*)(&As[(wm + mt * 16 + ln) * 64 + ks * 32 + quad * 8]);
#pragma unroll
            for (int nt = 0; nt < 4; nt++)
                bfg[nt] = *(const bf16x8*)(&Bs[(wn + nt * 16 + ln) * 64 + ks * 32 + quad * 8]);
#pragma unroll
            for (int mt = 0; mt < 4; mt++)
#pragma unroll
                for (int nt = 0; nt < 4; nt++)
                    acc[mt][nt] = __builtin_amdgcn_mfma_f32_16x16x32_bf16(
                        af[mt], bfg[nt], acc[mt][nt], 0, 0, 0);
        }
    }

#pragma unroll
    for (int nt = 0; nt < 4; nt++) {
        int n = n0 + wn + nt * 16 + ln;
        float bn = bias[n];
#pragma unroll
        for (int mt = 0; mt < 4; mt++) {
#pragma unroll
            for (int r = 0; r < 4; r++) {
                int m = m0 + wm + mt * 16 + quad * 4 + r;
                float val = (acc[mt][nt][r] + bn) * scale;
                if (OUTBF16) ((u16*)Cp)[(size_t)m * N + n] = f2bf(val);
                else         ((float*)Cp)[(size_t)m * N + n] = val;
            }
        }
    }
}

// ---------------------------------------------------------------------------
// vt[b][h][d][s] = v_bf[b][s][h*64+d]
__global__ __launch_bounds__(256) void transpose_v_kernel(
    const u16* __restrict__ vb, u16* __restrict__ vt)
{
    __shared__ __align__(16) u16 t[64 * 72];
    const int bh = blockIdx.y, b = bh >> 4, h = bh & 15;
    const int s0 = blockIdx.x * 64;
    const int tid = threadIdx.x;
#pragma unroll
    for (int i = 0; i < 2; i++) {
        int chunk = tid + 256 * i;                    // 512 = 64 rows x 8
        int row = chunk >> 3, c = chunk & 7;
        u16x8 v = *(const u16x8*)(vb + (size_t)(b * SS + s0 + row) * EE + h * 64 + c * 8);
        *(u16x8*)(t + row * 72 + c * 8) = v;
    }
    __syncthreads();
#pragma unroll
    for (int i = 0; i < 2; i++) {
        int chunk = tid + 256 * i;
        int d = chunk >> 3, c = chunk & 7;
        u16x8 o;
#pragma unroll
        for (int j = 0; j < 8; j++) o[j] = t[(c * 8 + j) * 72 + d];
        *(u16x8*)(vt + (size_t)(bh * 64 + d) * SS + s0 + c * 8) = o;
    }
}

// ---------------------------------------------------------------------------
// Attention: per block 128 q-rows of one (b,h); 4 waves, 32 q/wave.
// S^T = K*Q^T; q pre-scaled by 0.125*log2e, comb in log2 domain -> bare exp2.
// Bias fragments init the QK accumulator (loaded before mid-barrier so its
// vmcnt(0) drain covers them). launch_bounds(256,2): kernel needs ~184
// unified regs; capping at 3 blocks/CU spills to scratch (round-1: +124MB
// WRITE_SIZE, dur +90us). 2 blocks/CU is the correct operating point.
__global__ __launch_bounds__(256, 2) void attn_kernel(
    const u16* __restrict__ qb,   // [B,L,E] bf16, pre-scaled (0.125*log2e)
    const u16* __restrict__ kb,   // [B,S,E] bf16
    const u16* __restrict__ vt,   // [B*H,64,S] bf16
    const u16* __restrict__ comb, // [L,S] bf16 (mask+bias)*log2e
    u16* __restrict__ attn)       // [B,L,E] bf16
{
    __shared__ __align__(16) u16 KPs[128 * 136];  // union: K tile (stride 72) / P^T (stride 136)
    __shared__ __align__(16) u16 Vs[64 * 136];    // V^T tile [d][s]
    const int tid = threadIdx.x, lane = tid & 63, wave = tid >> 6;
    const int quad = lane >> 4, ln = lane & 15;
    const int bh = blockIdx.y, b = bh >> 4, h = bh & 15;
    const int q0 = blockIdx.x * 128;
    const int qloc0 = wave * 32;                  // wave's first local q row

    bf16x8 qf[2][2];
#pragma unroll
    for (int qg = 0; qg < 2; qg++)
#pragma unroll
        for (int ks = 0; ks < 2; ks++)
            qf[qg][ks] = *(const bf16x8*)(qb + (size_t)(b * LL + q0 + qloc0 + 16 * qg + ln) * EE
                                          + h * 64 + ks * 32 + quad * 8);

    const u16* cb0 = comb + (size_t)(q0 + qloc0 + ln) * SS + quad * 4;  // qg=0
    const u16* cb1 = cb0 + (size_t)16 * SS;                              // qg=1

    f32x4 o[4][2];
#pragma unroll
    for (int mt = 0; mt < 4; mt++) { o[mt][0] = (f32x4){0,0,0,0}; o[mt][1] = (f32x4){0,0,0,0}; }
    f32x4 ls0 = (f32x4){0,0,0,0}, ls1 = (f32x4){0,0,0,0};   // 4 independent sum chains each

    u16x8 kreg[4], vreg[4];
    auto load_kv = [&](int s0) {
#pragma unroll
        for (int i = 0; i < 4; i++) {
            int chunk = tid + 256 * i, row = chunk >> 3, c = chunk & 7;   // 128 x 8
            kreg[i] = *(const u16x8*)(kb + (size_t)(b * SS + s0 + row) * EE + h * 64 + c * 8);
        }
#pragma unroll
        for (int i = 0; i < 4; i++) {
            int chunk = tid + 256 * i, row = chunk >> 4, c = chunk & 15;  // 64 x 16
            vreg[i] = *(const u16x8*)(vt + (size_t)(bh * 64 + row) * SS + s0 + c * 8);
        }
    };
    load_kv(0);

    for (int s0 = 0; s0 < SS; s0 += 128) {
        __syncthreads();                           // prev iter's P/V LDS reads done
#pragma unroll
        for (int i = 0; i < 4; i++) {              // K tile -> union (stride 72)
            int chunk = tid + 256 * i, row = chunk >> 3, c = chunk & 7;
            *(u16x8*)(KPs + row * 72 + c * 8) = kreg[i];
        }
#pragma unroll
        for (int i = 0; i < 4; i++) {              // V^T tile
            int chunk = tid + 256 * i, row = chunk >> 4, c = chunk & 15;
            *(u16x8*)(Vs + row * 136 + c * 8) = vreg[i];
        }
        // bias fragments: issued before the barrier -> its vmcnt(0) drain covers them
        u16x4 bfr[8][2];
#pragma unroll
        for (int mt = 0; mt < 8; mt++) {
            bfr[mt][0] = *(const u16x4*)(cb0 + s0 + mt * 16);
            bfr[mt][1] = *(const u16x4*)(cb1 + s0 + mt * 16);
        }
        __syncthreads();

        if (s0 + 128 < SS) load_kv(s0 + 128);      // prefetch next K/V into regs

        // S^T accumulator initialized with bias (log2 domain)
        f32x4 st[8][2];
#pragma unroll
        for (int mt = 0; mt < 8; mt++)
#pragma unroll
            for (int r = 0; r < 4; r++) {
                st[mt][0][r] = bf2f(bfr[mt][0][r]);
                st[mt][1][r] = bf2f(bfr[mt][1][r]);
            }

        // S^T[s][q] = bias + sum_d K[s][d] * Q[q][d]
        __builtin_amdgcn_s_setprio(1);
#pragma unroll
        for (int mt = 0; mt < 8; mt++) {
            bf16x8 a0 = *(const bf16x8*)(KPs + (mt * 16 + ln) * 72 + quad * 8);
            bf16x8 a1 = *(const bf16x8*)(KPs + (mt * 16 + ln) * 72 + 32 + quad * 8);
            st[mt][0] = __builtin_amdgcn_mfma_f32_16x16x32_bf16(a0, qf[0][0], st[mt][0], 0, 0, 0);
            st[mt][0] = __builtin_amdgcn_mfma_f32_16x16x32_bf16(a1, qf[0][1], st[mt][0], 0, 0, 0);
            st[mt][1] = __builtin_amdgcn_mfma_f32_16x16x32_bf16(a0, qf[1][0], st[mt][1], 0, 0, 0);
            st[mt][1] = __builtin_amdgcn_mfma_f32_16x16x32_bf16(a1, qf[1][1], st[mt][1], 0, 0, 0);
        }
        __builtin_amdgcn_s_setprio(0);

        // exp2 + native bf16 pack (compiler emits v_cvt_pk_bf16_f32)
        bf16x4 p[8][2];
#pragma unroll
        for (int mt = 0; mt < 8; mt++)
#pragma unroll
            for (int r = 0; r < 4; r++) {
                float e0 = __builtin_amdgcn_exp2f(st[mt][0][r]);
                float e1 = __builtin_amdgcn_exp2f(st[mt][1][r]);
                ls0[r] += e0; ls1[r] += e1;
                p[mt][0][r] = (__bf16)e0;
                p[mt][1][r] = (__bf16)e1;
            }

        __syncthreads();                           // all waves done reading K tile

#pragma unroll
        for (int mt = 0; mt < 8; mt++) {           // P^T -> union (stride 136), wave-private rows
            *(bf16x4*)(KPs + (qloc0 + ln) * 136 + mt * 16 + quad * 4)      = p[mt][0];
            *(bf16x4*)(KPs + (qloc0 + 16 + ln) * 136 + mt * 16 + quad * 4) = p[mt][1];
        }

        // O^T[d][q] += sum_s V^T[d][s] * P[s][q]
#pragma unroll
        for (int ks = 0; ks < 4; ks++) {
            bf16x8 pf0 = *(const bf16x8*)(KPs + (qloc0 + ln) * 136 + ks * 32 + quad * 8);
            bf16x8 pf1 = *(const bf16x8*)(KPs + (qloc0 + 16 + ln) * 136 + ks * 32 + quad * 8);
            __builtin_amdgcn_s_setprio(1);
#pragma unroll
            for (int mt = 0; mt < 4; mt++) {
                bf16x8 a = *(const bf16x8*)(Vs + (mt * 16 + ln) * 136 + ks * 32 + quad * 8);
                o[mt][0] = __builtin_amdgcn_mfma_f32_16x16x32_bf16(a, pf0, o[mt][0], 0, 0, 0);
                o[mt][1] = __builtin_amdgcn_mfma_f32_16x16x32_bf16(a, pf1, o[mt][1], 0, 0, 0);
            }
            __builtin_amdgcn_s_setprio(0);
        }
    }

    // softmax denominator: merge 4 chains, then reduce across quads
    float lsum0 = (ls0[0] + ls0[1]) + (ls0[2] + ls0[3]);
    float lsum1 = (ls1[0] + ls1[1]) + (ls1[2] + ls1[3]);
    lsum0 += __shfl_xor(lsum0, 16); lsum0 += __shfl_xor(lsum0, 32);
    lsum1 += __shfl_xor(lsum1, 16); lsum1 += __shfl_xor(lsum1, 32);
    float inv0 = 1.f / lsum0, inv1 = 1.f / lsum1;

    // O^T -> LDS (wave-private rows) -> coalesced store
#pragma unroll
    for (int mt = 0; mt < 4; mt++) {
        bf16x4 p0, p1;
#pragma unroll
        for (int r = 0; r < 4; r++) {
            p0[r] = (__bf16)(o[mt][0][r] * inv0);
            p1[r] = (__bf16)(o[mt][1][r] * inv1);
        }
        *(bf16x4*)(KPs + (qloc0 + ln) * 136 + mt * 16 + quad * 4)      = p0;
        *(bf16x4*)(KPs + (qloc0 + 16 + ln) * 136 + mt * 16 + quad * 4) = p1;
    }
#pragma unroll
    for (int i = 0; i < 4; i++) {
        int j = lane + 64 * i;                     // 256 chunks over wave's 32 rows
        int r = j >> 3, c = j & 7;
        u16x8 v = *(const u16x8*)(KPs + (qloc0 + r) * 136 + c * 8);
        *(u16x8*)(attn + (size_t)(b * LL + q0 + qloc0 + r) * EE + h * 64 + c * 8) = v;
    }
}

// ---------------------------------------------------------------------------
extern "C" void kernel_launch(void* const* d_in, const int* in_sizes, int n_in,
                              void* d_out, int out_size, void* d_ws, size_t ws_size,
                              hipStream_t stream)
{
    (void)in_sizes; (void)n_in; (void)out_size; (void)ws_size;
    const float* query     = (const float*)d_in[0];
    const float* key       = (const float*)d_in[1];
    const float* value     = (const float*)d_in[2];
    const float* attn_bias = (const float*)d_in[3];
    const float* attn_mask = (const float*)d_in[4];
    const float* Wqkv      = (const float*)d_in[5];
    const float* bqkv      = (const float*)d_in[6];
    const float* Wo        = (const float*)d_in[7];
    const float* bo        = (const float*)d_in[8];
    float* out = (float*)d_out;

    // workspace layout (~100.7 MB, unchanged)
    u16* wq_bf = (u16*)d_ws;                 // 3*EE*EE
    u16* wo_bf = wq_bf + 3 * EE * EE;        // EE*EE
    u16* comb  = wo_bf + EE * EE;            // LL*SS
    u16* q_bf  = comb + (size_t)LL * SS;     // MM*EE each:
    u16* k_bf  = q_bf + (size_t)MM * EE;
    u16* v_bf  = k_bf + (size_t)MM * EE;
    u16* vtr   = v_bf + (size_t)MM * EE;
    u16* attnb = vtr  + (size_t)MM * EE;
    u16* tmp   = attnb;   // input-cast scratch; free until attn_kernel (stream-serial)

    f32_to_bf16_kernel<<<3 * EE * EE / 2048, 256, 0, stream>>>(Wqkv, wq_bf);
    f32_to_bf16_kernel<<<EE * EE / 2048, 256, 0, stream>>>(Wo, wo_bf);
    combine_bias_kernel<<<(LL * SS) / 2048, 256, 0, stream>>>(attn_bias, attn_mask, comb);

    dim3 gg(MM / 128, EE / 128);
    // q pre-scaled by SCALING * log2(e) so attn uses bare exp2
    f32_to_bf16_kernel<<<(int)((size_t)MM * EE / 2048), 256, 0, stream>>>(query, tmp);
    gemm_bt_bf16<1><<<gg, 256, 0, stream>>>(tmp, wq_bf,              bqkv,          q_bf, MM, EE, EE, 0.125f * LOG2E);
    f32_to_bf16_kernel<<<(int)((size_t)MM * EE / 2048), 256, 0, stream>>>(key, tmp);
    gemm_bt_bf16<1><<<gg, 256, 0, stream>>>(tmp, wq_bf + EE * EE,     bqkv + EE,     k_bf, MM, EE, EE, 1.f);
    f32_to_bf16_kernel<<<(int)((size_t)MM * EE / 2048), 256, 0, stream>>>(value, tmp);
    gemm_bt_bf16<1><<<gg, 256, 0, stream>>>(tmp, wq_bf + 2 * EE * EE, bqkv + 2 * EE, v_bf, MM, EE, EE, 1.f);

    transpose_v_kernel<<<dim3(SS / 64, BB * HH), 256, 0, stream>>>(v_bf, vtr);

    attn_kernel<<<dim3(LL / 128, BB * HH), 256, 0, stream>>>(q_bf, k_bf, vtr, comb, attnb);

    gemm_bt_bf16<0><<<gg, 256, 0, stream>>>(attnb, wo_bf, bo, out, MM, EE, EE, 1.f);
}

// Round 3
// 434.100 us; speedup vs baseline: 1.2820x; 1.0480x over previous
//
#include <hip/hip_runtime.h>
#include <hip/hip_bf16.h>

// Problem constants
#define BB 4
#define LL 2048
#define SS 2048
#define EE 1024
#define HH 16
#define DD 64
#define MM (BB * LL)   // 8192 rows for all projections
#define LOG2E 1.44269504088896340736f

typedef unsigned short u16;
typedef u16   u16x4  __attribute__((ext_vector_type(4)));
typedef u16   u16x8  __attribute__((ext_vector_type(8)));
typedef float f32x4  __attribute__((ext_vector_type(4)));
typedef __bf16 bf16x4 __attribute__((ext_vector_type(4)));
typedef __bf16 bf16x8 __attribute__((ext_vector_type(8)));

__device__ __forceinline__ u16 f2bf(float x) {
    unsigned u = __float_as_uint(x);
    u += 0x7fffu + ((u >> 16) & 1u);       // RNE (inputs finite)
    return (u16)(u >> 16);
}
__device__ __forceinline__ float bf2f(u16 b) {
    return __uint_as_float(((unsigned)b) << 16);
}

// async global->LDS, 16B per lane; LDS dest is wave-uniform base + lane*16
__device__ __forceinline__ void gload16(const u16* g, u16* l) {
    __builtin_amdgcn_global_load_lds(
        (const __attribute__((address_space(1))) void*)g,
        (__attribute__((address_space(3))) void*)l, 16, 0, 0);
}

// ---------------------------------------------------------------------------
// Generic fp32 -> bf16 cast, 8 elems/thread (weights only now)
__global__ __launch_bounds__(256) void f32_to_bf16_kernel(
    const float* __restrict__ in, u16* __restrict__ out)
{
    size_t idx = ((size_t)blockIdx.x * 256 + threadIdx.x) * 8;
    f32x4 a = *(const f32x4*)(in + idx);
    f32x4 b = *(const f32x4*)(in + idx + 4);
    u16x8 o;
#pragma unroll
    for (int j = 0; j < 4; j++) { o[j] = f2bf(a[j]); o[4 + j] = f2bf(b[j]); }
    *(u16x8*)(out + idx) = o;
}

// ---------------------------------------------------------------------------
// comb[l][s] = bf16((attn_bias + attn_mask) * log2(e))  -- log2 domain for exp2
__global__ __launch_bounds__(256) void combine_bias_kernel(
    const float* __restrict__ bias, const float* __restrict__ mask,
    u16* __restrict__ comb)
{
    int idx = (blockIdx.x * 256 + threadIdx.x) * 8;
    f32x4 a0 = *(const f32x4*)(bias + idx);
    f32x4 a1 = *(const f32x4*)(bias + idx + 4);
    f32x4 m0 = *(const f32x4*)(mask + idx);
    f32x4 m1 = *(const f32x4*)(mask + idx + 4);
    u16x8 o;
#pragma unroll
    for (int j = 0; j < 4; j++) {
        o[j]     = f2bf((a0[j] + m0[j]) * LOG2E);
        o[4 + j] = f2bf((a1[j] + m1[j]) * LOG2E);
    }
    *(u16x8*)(comb + idx) = o;
}

// ---------------------------------------------------------------------------
// C[m][n] = (sum_k A[m][k]*Bw[n][k] + bias[n]) * scale
// Fixed shape: M=8192, N=1024, K=1024, grid 512 (1D), 128x128 tile, BK=64.
// ABF16=0: A fp32, reg-staged + converted during LDS write (fuses the cast).
// ABF16=1: A bf16 via global_load_lds.  B always bf16 via global_load_lds.
// XCD swizzle: each XCD gets runs of 8 consecutive vids = 1 m-tile x all 8
// n-tiles -> B panel (2MB) L2-resident per XCD, A panel consumed on one XCD.
// VOUT=1 (v-projection): epilogue transposes via LDS and writes
// vt[b*16+h][d][s] directly (kills the separate transpose kernel).
template <int ABF16, int OUTBF16, int VOUT>
__global__ __launch_bounds__(256, 2) void gemm_bt(
    const void* __restrict__ Ap, const u16* __restrict__ Bw,
    const float* __restrict__ bias, void* __restrict__ Cp,
    int M, int N, int K, float scale)
{
    // LDS: As stride 72 (fp32 path, de-conflicts ds_write) or 64 (gload path);
    // Bs stride 64 (gload).  Union reused as 128x136 transpose buffer (VOUT).
    __shared__ __align__(16) u16 SH[128 * 72 + 128 * 64];  // 34816 B
    constexpr int ASTR = ABF16 ? 64 : 72;
    u16* As = SH;
    u16* Bs = SH + 128 * ASTR;
    u16* Tr = SH;

    const int tid = threadIdx.x;
    const int lane = tid & 63, wave = tid >> 6;
    const int quad = lane >> 4, ln = lane & 15;
    const int wm = (wave & 1) * 64, wn = (wave >> 1) * 64;

    // XCD-aware swizzle (assumes xcd = bid % 8; perf-only heuristic)
    const int bid = blockIdx.x;
    const int vid = (bid & 7) * 8 + ((bid >> 3) & 7) + (bid >> 6) * 64;
    const int m0 = (vid >> 3) * 128, n0 = (vid & 7) * 128;

    const int r8 = lane >> 3, c8 = lane & 7;
    const float* Af = (const float*)Ap;
    const u16*   Ab = (const u16*)Ap + (size_t)m0 * K + c8 * 8;
    const u16*   Bg = Bw + (size_t)n0 * K + c8 * 8;

    f32x4 acc[4][4];
#pragma unroll
    for (int mt = 0; mt < 4; mt++)
#pragma unroll
        for (int nt = 0; nt < 4; nt++) acc[mt][nt] = (f32x4){0.f, 0.f, 0.f, 0.f};

    f32x4 apf[8];   // A prefetch (fp32 path)

    auto load_a = [&](int k0) {
        if (!ABF16) {
#pragma unroll
            for (int i = 0; i < 8; i++) {
                int chunk = tid + 256 * i, row = chunk >> 4, c = chunk & 15;
                apf[i] = *(const f32x4*)(Af + (size_t)(m0 + row) * K + k0 + c * 4);
            }
        }
    };

    load_a(0);

    const int KT = K >> 6;
    for (int kt = 0; kt < KT; kt++) {
        const int k0 = kt << 6;
        __syncthreads();                       // prev compute done reading LDS
        // B (and A if bf16) via async global->LDS
#pragma unroll
        for (int i = 0; i < 4; i++) {
            int ch = i * 4 + wave;             // 16 chunks of 1KB
            int row = ch * 8 + r8;
            gload16(Bg + (size_t)row * K + k0, &Bs[ch * 512]);
            if (ABF16) gload16(Ab + (size_t)row * K + k0, &As[ch * 512]);
        }
        if (!ABF16) {                          // A: regs -> bf16 -> LDS
#pragma unroll
            for (int i = 0; i < 8; i++) {
                int chunk = tid + 256 * i, row = chunk >> 4, c = chunk & 15;
                u16x4 o;
#pragma unroll
                for (int j = 0; j < 4; j++) o[j] = f2bf(apf[i][j]);
                *(u16x4*)(As + row * ASTR + c * 4) = o;
            }
        }
        __syncthreads();                       // drains vmcnt (gload) + lgkm

        if (kt + 1 < KT) load_a(k0 + 64);      // overlap next A with compute

#pragma unroll
        for (int ks = 0; ks < 2; ks++) {
            bf16x8 af[4], bfg[4];
#pragma unroll
            for (int mt = 0; mt < 4; mt++)
                af[mt] = *(const bf16x8*)(&As[(wm + mt * 16 + ln) * ASTR + ks * 32 + quad * 8]);
#pragma unroll
            for (int nt = 0; nt < 4; nt++)
                bfg[nt] = *(const bf16x8*)(&Bs[(wn + nt * 16 + ln) * 64 + ks * 32 + quad * 8]);
#pragma unroll
            for (int mt = 0; mt < 4; mt++)
#pragma unroll
                for (int nt = 0; nt < 4; nt++)
                    acc[mt][nt] = __builtin_amdgcn_mfma_f32_16x16x32_bf16(
                        af[mt], bfg[nt], acc[mt][nt], 0, 0, 0);
        }
    }

    if (VOUT) {
        // transpose epilogue: acc -> LDS [n_local][m_local] -> vt[bh][d][s]
        __syncthreads();
#pragma unroll
        for (int nt = 0; nt < 4; nt++) {
            int nl = wn + nt * 16 + ln;
            float bn = bias[n0 + nl];
#pragma unroll
            for (int mt = 0; mt < 4; mt++)
#pragma unroll
                for (int r = 0; r < 4; r++) {
                    int ml = wm + mt * 16 + quad * 4 + r;
                    Tr[nl * 136 + ml] = f2bf(acc[mt][nt][r] + bn);   // scale==1
                }
        }
        __syncthreads();
        const int bq = m0 >> 11;               // batch index
        const int s0 = m0 & 2047;              // s offset within batch
#pragma unroll
        for (int i = 0; i < 8; i++) {
            int chunk = tid + 256 * i;         // 2048 = 128 rows x 16 chunks
            int row = chunk >> 4, c = chunk & 15;
            u16x8 v = *(const u16x8*)(Tr + row * 136 + c * 8);
            int n = n0 + row;
            int h = n >> 6, d = n & 63;
            *(u16x8*)(((u16*)Cp) + ((size_t)((bq * 16 + h) * 64 + d)) * SS + s0 + c * 8) = v;
        }
    } else {
#pragma unroll
        for (int nt = 0; nt < 4; nt++) {
            int n = n0 + wn + nt * 16 + ln;
            float bn = bias[n];
#pragma unroll
            for (int mt = 0; mt < 4; mt++) {
#pragma unroll
                for (int r = 0; r < 4; r++) {
                    int m = m0 + wm + mt * 16 + quad * 4 + r;
                    float val = (acc[mt][nt][r] + bn) * scale;
                    if (OUTBF16) ((u16*)Cp)[(size_t)m * N + n] = f2bf(val);
                    else         ((float*)Cp)[(size_t)m * N + n] = val;
                }
            }
        }
    }
}

// ---------------------------------------------------------------------------
// Attention: per block 128 q-rows of one (b,h); 4 waves, 32 q/wave.
// S^T = K*Q^T; q pre-scaled by 0.125*log2e, comb in log2 domain -> bare exp2.
// Grid 1024 1D with XCD swizzle: each XCD owns 8 bh x all 16 q-tiles ->
// K/V working set 4MB = one L2; comb streams via L3.
__global__ __launch_bounds__(256, 2) void attn_kernel(
    const u16* __restrict__ qb,   // [B,L,E] bf16, pre-scaled (0.125*log2e)
    const u16* __restrict__ kb,   // [B,S,E] bf16
    const u16* __restrict__ vt,   // [B*H,64,S] bf16
    const u16* __restrict__ comb, // [L,S] bf16 (mask+bias)*log2e
    u16* __restrict__ attn)       // [B,L,E] bf16
{
    __shared__ __align__(16) u16 KPs[128 * 136];  // union: K tile (stride 72) / P^T (stride 136)
    __shared__ __align__(16) u16 Vs[64 * 136];    // V^T tile [d][s]
    const int tid = threadIdx.x, lane = tid & 63, wave = tid >> 6;
    const int quad = lane >> 4, ln = lane & 15;

    const int bid = blockIdx.x;                   // XCD swizzle (bh-major vids)
    const int vid = (bid & 7) * 128 + (bid >> 3);
    const int bh = vid >> 4, b = bh >> 4, h = bh & 15;
    const int q0 = (vid & 15) * 128;
    const int qloc0 = wave * 32;                  // wave's first local q row

    bf16x8 qf[2][2];
#pragma unroll
    for (int qg = 0; qg < 2; qg++)
#pragma unroll
        for (int ks = 0; ks < 2; ks++)
            qf[qg][ks] = *(const bf16x8*)(qb + (size_t)(b * LL + q0 + qloc0 + 16 * qg + ln) * EE
                                          + h * 64 + ks * 32 + quad * 8);

    const u16* cb0 = comb + (size_t)(q0 + qloc0 + ln) * SS + quad * 4;  // qg=0
    const u16* cb1 = cb0 + (size_t)16 * SS;                              // qg=1

    f32x4 o[4][2];
#pragma unroll
    for (int mt = 0; mt < 4; mt++) { o[mt][0] = (f32x4){0,0,0,0}; o[mt][1] = (f32x4){0,0,0,0}; }
    f32x4 ls0 = (f32x4){0,0,0,0}, ls1 = (f32x4){0,0,0,0};   // 4 independent sum chains each

    u16x8 kreg[4], vreg[4];
    auto load_kv = [&](int s0) {
#pragma unroll
        for (int i = 0; i < 4; i++) {
            int chunk = tid + 256 * i, row = chunk >> 3, c = chunk & 7;   // 128 x 8
            kreg[i] = *(const u16x8*)(kb + (size_t)(b * SS + s0 + row) * EE + h * 64 + c * 8);
        }
#pragma unroll
        for (int i = 0; i < 4; i++) {
            int chunk = tid + 256 * i, row = chunk >> 4, c = chunk & 15;  // 64 x 16
            vreg[i] = *(const u16x8*)(vt + (size_t)(bh * 64 + row) * SS + s0 + c * 8);
        }
    };
    load_kv(0);

    for (int s0 = 0; s0 < SS; s0 += 128) {
        __syncthreads();                           // prev iter's P/V LDS reads done
#pragma unroll
        for (int i = 0; i < 4; i++) {              // K tile -> union (stride 72)
            int chunk = tid + 256 * i, row = chunk >> 3, c = chunk & 7;
            *(u16x8*)(KPs + row * 72 + c * 8) = kreg[i];
        }
#pragma unroll
        for (int i = 0; i < 4; i++) {              // V^T tile
            int chunk = tid + 256 * i, row = chunk >> 4, c = chunk & 15;
            *(u16x8*)(Vs + row * 136 + c * 8) = vreg[i];
        }
        // bias fragments: issued before the barrier -> its vmcnt(0) drain covers them
        u16x4 bfr[8][2];
#pragma unroll
        for (int mt = 0; mt < 8; mt++) {
            bfr[mt][0] = *(const u16x4*)(cb0 + s0 + mt * 16);
            bfr[mt][1] = *(const u16x4*)(cb1 + s0 + mt * 16);
        }
        __syncthreads();

        if (s0 + 128 < SS) load_kv(s0 + 128);      // prefetch next K/V into regs

        // S^T accumulator initialized with bias (log2 domain)
        f32x4 st[8][2];
#pragma unroll
        for (int mt = 0; mt < 8; mt++)
#pragma unroll
            for (int r = 0; r < 4; r++) {
                st[mt][0][r] = bf2f(bfr[mt][0][r]);
                st[mt][1][r] = bf2f(bfr[mt][1][r]);
            }

        // S^T[s][q] = bias + sum_d K[s][d] * Q[q][d]
        __builtin_amdgcn_s_setprio(1);
#pragma unroll
        for (int mt = 0; mt < 8; mt++) {
            bf16x8 a0 = *(const bf16x8*)(KPs + (mt * 16 + ln) * 72 + quad * 8);
            bf16x8 a1 = *(const bf16x8*)(KPs + (mt * 16 + ln) * 72 + 32 + quad * 8);
            st[mt][0] = __builtin_amdgcn_mfma_f32_16x16x32_bf16(a0, qf[0][0], st[mt][0], 0, 0, 0);
            st[mt][0] = __builtin_amdgcn_mfma_f32_16x16x32_bf16(a1, qf[0][1], st[mt][0], 0, 0, 0);
            st[mt][1] = __builtin_amdgcn_mfma_f32_16x16x32_bf16(a0, qf[1][0], st[mt][1], 0, 0, 0);
            st[mt][1] = __builtin_amdgcn_mfma_f32_16x16x32_bf16(a1, qf[1][1], st[mt][1], 0, 0, 0);
        }
        __builtin_amdgcn_s_setprio(0);

        // exp2 + native bf16 pack (compiler emits v_cvt_pk_bf16_f32)
        bf16x4 p[8][2];
#pragma unroll
        for (int mt = 0; mt < 8; mt++)
#pragma unroll
            for (int r = 0; r < 4; r++) {
                float e0 = __builtin_amdgcn_exp2f(st[mt][0][r]);
                float e1 = __builtin_amdgcn_exp2f(st[mt][1][r]);
                ls0[r] += e0; ls1[r] += e1;
                p[mt][0][r] = (__bf16)e0;
                p[mt][1][r] = (__bf16)e1;
            }

        __syncthreads();                           // all waves done reading K tile

#pragma unroll
        for (int mt = 0; mt < 8; mt++) {           // P^T -> union (stride 136), wave-private rows
            *(bf16x4*)(KPs + (qloc0 + ln) * 136 + mt * 16 + quad * 4)      = p[mt][0];
            *(bf16x4*)(KPs + (qloc0 + 16 + ln) * 136 + mt * 16 + quad * 4) = p[mt][1];
        }

        // O^T[d][q] += sum_s V^T[d][s] * P[s][q]
#pragma unroll
        for (int ks = 0; ks < 4; ks++) {
            bf16x8 pf0 = *(const bf16x8*)(KPs + (qloc0 + ln) * 136 + ks * 32 + quad * 8);
            bf16x8 pf1 = *(const bf16x8*)(KPs + (qloc0 + 16 + ln) * 136 + ks * 32 + quad * 8);
            __builtin_amdgcn_s_setprio(1);
#pragma unroll
            for (int mt = 0; mt < 4; mt++) {
                bf16x8 a = *(const bf16x8*)(Vs + (mt * 16 + ln) * 136 + ks * 32 + quad * 8);
                o[mt][0] = __builtin_amdgcn_mfma_f32_16x16x32_bf16(a, pf0, o[mt][0], 0, 0, 0);
                o[mt][1] = __builtin_amdgcn_mfma_f32_16x16x32_bf16(a, pf1, o[mt][1], 0, 0, 0);
            }
            __builtin_amdgcn_s_setprio(0);
        }
    }

    // softmax denominator: merge 4 chains, then reduce across quads
    float lsum0 = (ls0[0] + ls0[1]) + (ls0[2] + ls0[3]);
    float lsum1 = (ls1[0] + ls1[1]) + (ls1[2] + ls1[3]);
    lsum0 += __shfl_xor(lsum0, 16); lsum0 += __shfl_xor(lsum0, 32);
    lsum1 += __shfl_xor(lsum1, 16); lsum1 += __shfl_xor(lsum1, 32);
    float inv0 = 1.f / lsum0, inv1 = 1.f / lsum1;

    // O^T -> LDS (wave-private rows) -> coalesced store
#pragma unroll
    for (int mt = 0; mt < 4; mt++) {
        bf16x4 p0, p1;
#pragma unroll
        for (int r = 0; r < 4; r++) {
            p0[r] = (__bf16)(o[mt][0][r] * inv0);
            p1[r] = (__bf16)(o[mt][1][r] * inv1);
        }
        *(bf16x4*)(KPs + (qloc0 + ln) * 136 + mt * 16 + quad * 4)      = p0;
        *(bf16x4*)(KPs + (qloc0 + 16 + ln) * 136 + mt * 16 + quad * 4) = p1;
    }
#pragma unroll
    for (int i = 0; i < 4; i++) {
        int j = lane + 64 * i;                     // 256 chunks over wave's 32 rows
        int r = j >> 3, c = j & 7;
        u16x8 v = *(const u16x8*)(KPs + (qloc0 + r) * 136 + c * 8);
        *(u16x8*)(attn + (size_t)(b * LL + q0 + qloc0 + r) * EE + h * 64 + c * 8) = v;
    }
}

// ---------------------------------------------------------------------------
extern "C" void kernel_launch(void* const* d_in, const int* in_sizes, int n_in,
                              void* d_out, int out_size, void* d_ws, size_t ws_size,
                              hipStream_t stream)
{
    (void)in_sizes; (void)n_in; (void)out_size; (void)ws_size;
    const float* query     = (const float*)d_in[0];
    const float* key       = (const float*)d_in[1];
    const float* value     = (const float*)d_in[2];
    const float* attn_bias = (const float*)d_in[3];
    const float* attn_mask = (const float*)d_in[4];
    const float* Wqkv      = (const float*)d_in[5];
    const float* bqkv      = (const float*)d_in[6];
    const float* Wo        = (const float*)d_in[7];
    const float* bo        = (const float*)d_in[8];
    float* out = (float*)d_out;

    // workspace layout (same offsets as before; v_bf slot now unused)
    u16* wq_bf = (u16*)d_ws;                 // 3*EE*EE
    u16* wo_bf = wq_bf + 3 * EE * EE;        // EE*EE
    u16* comb  = wo_bf + EE * EE;            // LL*SS
    u16* q_bf  = comb + (size_t)LL * SS;     // MM*EE each:
    u16* k_bf  = q_bf + (size_t)MM * EE;
    u16* v_bf  = k_bf + (size_t)MM * EE;     // unused (kept for layout stability)
    u16* vtr   = v_bf + (size_t)MM * EE;
    u16* attnb = vtr  + (size_t)MM * EE;

    f32_to_bf16_kernel<<<3 * EE * EE / 2048, 256, 0, stream>>>(Wqkv, wq_bf);
    f32_to_bf16_kernel<<<EE * EE / 2048, 256, 0, stream>>>(Wo, wo_bf);
    combine_bias_kernel<<<(LL * SS) / 2048, 256, 0, stream>>>(attn_bias, attn_mask, comb);

    // projections: fp32 A fused-cast, bf16 weights; q pre-scaled by 0.125*log2e
    gemm_bt<0, 1, 0><<<512, 256, 0, stream>>>(query, wq_bf,               bqkv,          q_bf, MM, EE, EE, 0.125f * LOG2E);
    gemm_bt<0, 1, 0><<<512, 256, 0, stream>>>(key,   wq_bf + EE * EE,     bqkv + EE,     k_bf, MM, EE, EE, 1.f);
    gemm_bt<0, 1, 1><<<512, 256, 0, stream>>>(value, wq_bf + 2 * EE * EE, bqkv + 2 * EE, vtr,  MM, EE, EE, 1.f);

    attn_kernel<<<1024, 256, 0, stream>>>(q_bf, k_bf, vtr, comb, attnb);

    gemm_bt<1, 0, 0><<<512, 256, 0, stream>>>(attnb, wo_bf, bo, out, MM, EE, EE, 1.f);
}